// Round 1
// baseline (621.896 us; speedup 1.0000x reference)
//
#include <hip/hip_runtime.h>
#include <cstdint>
#include <cstddef>

static constexpr int Nn = 20000;
static constexpr int Ee = 320000;

__device__ __forceinline__ float lrelu02(float x){ return fmaxf(x, 0.2f*x); }

// ---------------- CSR build ----------------
__global__ void k_count(const int* __restrict__ dst, int* __restrict__ cnt){
  int e = blockIdx.x*256 + threadIdx.x;
  if (e < Ee) atomicAdd(&cnt[dst[e]], 1);
}

__global__ void k_scan(const int* __restrict__ cnt, int* __restrict__ row_start,
                       float* __restrict__ dinv){
  __shared__ int part[1024];
  int tid = threadIdx.x;
  const int PER = 20;                       // 1024*20 >= 20000
  int base = tid*PER;
  int s = 0;
  for (int i = 0; i < PER; ++i){ int idx = base+i; if (idx < Nn) s += cnt[idx]; }
  part[tid] = s; __syncthreads();
  for (int off = 1; off < 1024; off <<= 1){
    int v = (tid >= off) ? part[tid-off] : 0;
    __syncthreads();
    part[tid] += v;
    __syncthreads();
  }
  int run = (tid == 0) ? 0 : part[tid-1];
  for (int i = 0; i < PER; ++i){
    int idx = base+i;
    if (idx < Nn){
      row_start[idx] = run;
      int c = cnt[idx];
      run += c;
      dinv[idx] = rsqrtf((float)(c+1));     // +1 self-loop
    }
  }
  if (tid == 1023) row_start[Nn] = run;
}

__global__ void k_scatter(const int* __restrict__ src, const int* __restrict__ dst,
                          const int* __restrict__ row_start, int* __restrict__ fill,
                          int* __restrict__ csr){
  int e = blockIdx.x*256 + threadIdx.x;
  if (e < Ee){
    int d = dst[e];
    int pos = row_start[d] + atomicAdd(&fill[d], 1);
    csr[pos] = src[e];
  }
}

// ---------------- GCN aggregation: out[v] = dinv[v]*sum_u dinv[u]*h[u] + dinv[v]^2*h[v] ----------------
// POST: out = relu(val + bias) + skip
template<int C, bool POST>
__global__ __launch_bounds__(256) void k_gcn_agg(
    const float* __restrict__ h, const float* __restrict__ dinv,
    const int* __restrict__ row_start, const int* __restrict__ csr,
    const float* __restrict__ bias, const float* __restrict__ skip,
    float* __restrict__ out){
  int v = blockIdx.x*4 + (threadIdx.x >> 6);
  int lane = threadIdx.x & 63;
  int s = row_start[v], e = row_start[v+1];
  float dv = dinv[v];

  if constexpr (C == 32){
    int half = lane >> 5, c = lane & 31;
    float acc = 0.f;
    for (int i = s + half; i < e; i += 2){
      int u = csr[i];
      acc = fmaf(dinv[u], h[(size_t)u*32 + c], acc);
    }
    acc += __shfl_xor(acc, 32);
    float val = fmaf(acc, dv, h[(size_t)v*32 + c]*dv*dv);
    if (lane < 32) out[(size_t)v*32 + c] = val;
  } else if constexpr (C == 64){
    float acc = 0.f;
    for (int i = s; i < e; ++i){
      int u = csr[i];
      acc = fmaf(dinv[u], h[(size_t)u*64 + lane], acc);
    }
    float val = fmaf(acc, dv, h[(size_t)v*64 + lane]*dv*dv);
    if constexpr (POST){
      val = fmaxf(val + bias[lane], 0.f) + skip[(size_t)v*64 + lane];
    }
    out[(size_t)v*64 + lane] = val;
  } else {  // C == 128
    int c0 = lane*2;
    float ax = 0.f, ay = 0.f;
    for (int i = s; i < e; ++i){
      int u = csr[i];
      float du = dinv[u];
      float2 t = *(const float2*)&h[(size_t)u*128 + c0];
      ax = fmaf(du, t.x, ax);
      ay = fmaf(du, t.y, ay);
    }
    float2 hv = *(const float2*)&h[(size_t)v*128 + c0];
    float vx = fmaf(ax, dv, hv.x*dv*dv);
    float vy = fmaf(ay, dv, hv.y*dv*dv);
    if constexpr (POST){
      float2 bv = *(const float2*)&bias[c0];
      float2 sk = *(const float2*)&skip[(size_t)v*128 + c0];
      vx = fmaxf(vx + bv.x, 0.f) + sk.x;
      vy = fmaxf(vy + bv.y, 0.f) + sk.y;
    }
    *(float2*)&out[(size_t)v*128 + c0] = make_float2(vx, vy);
  }
}

// ---------------- GAT attention coefficients: aS[n,h]=<h3[n,h,:],att_s[h,:]>, same for aD ----------------
template<int CH>
__global__ __launch_bounds__(256) void k_attn_coef(
    const float* __restrict__ h, const float* __restrict__ att_s, const float* __restrict__ att_d,
    float* __restrict__ aS, float* __restrict__ aD){
  int v = blockIdx.x*4 + (threadIdx.x >> 6);
  int lane = threadIdx.x & 63;
  #pragma unroll
  for (int hh = 0; hh < 4; ++hh){
    float s = 0.f, d = 0.f;
    #pragma unroll
    for (int c = lane; c < CH; c += 64){
      float xv = h[(size_t)v*4*CH + hh*CH + c];
      s = fmaf(xv, att_s[hh*CH + c], s);
      d = fmaf(xv, att_d[hh*CH + c], d);
    }
    #pragma unroll
    for (int off = 32; off; off >>= 1){
      s += __shfl_xor(s, off);
      d += __shfl_xor(d, off);
    }
    if (lane == 0){ aS[v*4 + hh] = s; aD[v*4 + hh] = d; }
  }
}

// ---------------- GAT aggregation (4 heads), out = relu(agg + bias) ----------------
template<int CT>   // CT = 512 (CH=128) or 256 (CH=64)
__global__ __launch_bounds__(256) void k_gat_agg(
    const float* __restrict__ h, const float* __restrict__ aS, const float* __restrict__ aD,
    const int* __restrict__ row_start, const int* __restrict__ csr,
    const float* __restrict__ bias, float* __restrict__ out){
  int v = blockIdx.x*4 + (threadIdx.x >> 6);
  int lane = threadIdx.x & 63;
  int s0 = row_start[v], e0 = row_start[v+1];

  float4 tD = *(const float4*)&aD[v*4];
  float ad[4] = {tD.x, tD.y, tD.z, tD.w};
  float4 tS = *(const float4*)&aS[v*4];
  float asv[4] = {tS.x, tS.y, tS.z, tS.w};
  float lself[4];
  #pragma unroll
  for (int hh = 0; hh < 4; ++hh) lself[hh] = lrelu02(asv[hh] + ad[hh]);

  // online (max, sumexp) per head; lane 0 seeds with the self-loop logit
  float m[4], sd[4];
  #pragma unroll
  for (int hh = 0; hh < 4; ++hh){
    m[hh]  = (lane == 0) ? lself[hh] : -1e30f;
    sd[hh] = (lane == 0) ? 1.f : 0.f;
  }
  for (int i = s0 + lane; i < e0; i += 64){
    int u = csr[i];
    float4 a4 = *(const float4*)&aS[u*4];
    float av[4] = {a4.x, a4.y, a4.z, a4.w};
    #pragma unroll
    for (int hh = 0; hh < 4; ++hh){
      float l  = lrelu02(av[hh] + ad[hh]);
      float mn = fmaxf(m[hh], l);
      sd[hh] = sd[hh]*__expf(m[hh]-mn) + __expf(l-mn);
      m[hh] = mn;
    }
  }
  #pragma unroll
  for (int off = 32; off; off >>= 1){
    #pragma unroll
    for (int hh = 0; hh < 4; ++hh){
      float mo = __shfl_xor(m[hh], off);
      float so = __shfl_xor(sd[hh], off);
      float mn = fmaxf(m[hh], mo);
      sd[hh] = sd[hh]*__expf(m[hh]-mn) + so*__expf(mo-mn);
      m[hh] = mn;
    }
  }
  float rd[4], als[4];
  #pragma unroll
  for (int hh = 0; hh < 4; ++hh){
    rd[hh]  = 1.f / sd[hh];
    als[hh] = __expf(lself[hh] - m[hh]) * rd[hh];
  }

  const int c0 = lane*4;
  const int h0 = (CT == 512) ? (lane >> 5) : (lane >> 4);
  const int c1 = 256 + lane*4;            // CT==512 only
  const int h1 = 2 + (lane >> 5);

  float4 acc0, acc1;
  {
    float4 hv = *(const float4*)&h[(size_t)v*CT + c0];
    float a = als[h0];
    acc0 = make_float4(a*hv.x, a*hv.y, a*hv.z, a*hv.w);
  }
  if constexpr (CT == 512){
    float4 hv = *(const float4*)&h[(size_t)v*CT + c1];
    float a = als[h1];
    acc1 = make_float4(a*hv.x, a*hv.y, a*hv.z, a*hv.w);
  }

  for (int i = s0; i < e0; ++i){
    int u = csr[i];
    float4 a4 = *(const float4*)&aS[u*4];
    float av[4] = {a4.x, a4.y, a4.z, a4.w};
    float al[4];
    #pragma unroll
    for (int hh = 0; hh < 4; ++hh){
      float l = lrelu02(av[hh] + ad[hh]);
      al[hh] = __expf(l - m[hh]) * rd[hh];
    }
    float4 hv = *(const float4*)&h[(size_t)u*CT + c0];
    float a = al[h0];
    acc0.x = fmaf(a, hv.x, acc0.x);
    acc0.y = fmaf(a, hv.y, acc0.y);
    acc0.z = fmaf(a, hv.z, acc0.z);
    acc0.w = fmaf(a, hv.w, acc0.w);
    if constexpr (CT == 512){
      float4 hv1 = *(const float4*)&h[(size_t)u*CT + c1];
      float a1 = al[h1];
      acc1.x = fmaf(a1, hv1.x, acc1.x);
      acc1.y = fmaf(a1, hv1.y, acc1.y);
      acc1.z = fmaf(a1, hv1.z, acc1.z);
      acc1.w = fmaf(a1, hv1.w, acc1.w);
    }
  }

  {
    float4 bv = *(const float4*)&bias[c0];
    float4 o;
    o.x = fmaxf(acc0.x + bv.x, 0.f);
    o.y = fmaxf(acc0.y + bv.y, 0.f);
    o.z = fmaxf(acc0.z + bv.z, 0.f);
    o.w = fmaxf(acc0.w + bv.w, 0.f);
    *(float4*)&out[(size_t)v*CT + c0] = o;
  }
  if constexpr (CT == 512){
    float4 bv = *(const float4*)&bias[c1];
    float4 o;
    o.x = fmaxf(acc1.x + bv.x, 0.f);
    o.y = fmaxf(acc1.y + bv.y, 0.f);
    o.z = fmaxf(acc1.z + bv.z, 0.f);
    o.w = fmaxf(acc1.w + bv.w, 0.f);
    *(float4*)&out[(size_t)v*CT + c1] = o;
  }
}

// ---------------- dense matmul: out[n,j] = sum_k A[n,k]*W[k,j] (+bias)(+relu) ----------------
// grid.x = Nn/32 row blocks; grid.y = J/(64*CP) column chunks; block = 256 (4 waves x 8 rows)
template<int K, int J, int CP, bool BIAS, bool RELU>
__global__ __launch_bounds__(256) void k_mm(
    const float* __restrict__ A, const float* __restrict__ W,
    const float* __restrict__ bias, float* __restrict__ out){
  __shared__ float As[32*K];
  const int tid = threadIdx.x;
  const int rb  = blockIdx.x;

  const float4* srcp = (const float4*)(A + (size_t)rb*32*K);
  float4* dstS = (float4*)As;
  #pragma unroll 4
  for (int i = tid; i < 32*K/4; i += 256) dstS[i] = srcp[i];
  __syncthreads();

  const int wave = tid >> 6, lane = tid & 63;
  const int r0 = wave*8;
  const int col0 = blockIdx.y*(64*CP) + lane;

  float acc[8][CP];
  #pragma unroll
  for (int r = 0; r < 8; ++r)
    #pragma unroll
    for (int c = 0; c < CP; ++c) acc[r][c] = 0.f;

  for (int k0 = 0; k0 < K; k0 += 4){
    float4 a4[8];
    #pragma unroll
    for (int r = 0; r < 8; ++r) a4[r] = *(const float4*)&As[(r0+r)*K + k0];
    #pragma unroll
    for (int kk = 0; kk < 4; ++kk){
      float wv[CP];
      #pragma unroll
      for (int c = 0; c < CP; ++c) wv[c] = W[(size_t)(k0+kk)*J + col0 + c*64];
      #pragma unroll
      for (int r = 0; r < 8; ++r){
        float a = (kk==0) ? a4[r].x : (kk==1) ? a4[r].y : (kk==2) ? a4[r].z : a4[r].w;
        #pragma unroll
        for (int c = 0; c < CP; ++c) acc[r][c] = fmaf(a, wv[c], acc[r][c]);
      }
    }
  }

  #pragma unroll
  for (int c = 0; c < CP; ++c){
    int col = col0 + c*64;
    float bv = 0.f;
    if constexpr (BIAS) bv = bias[col];
    #pragma unroll
    for (int r = 0; r < 8; ++r){
      float val = acc[r][c] + bv;
      if constexpr (RELU) val = fmaxf(val, 0.f);
      out[(size_t)(rb*32 + r0 + r)*J + col] = val;
    }
  }
}

// ---------------- final 128 -> 4 matmul (+bias), one wave per row ----------------
__global__ __launch_bounds__(256) void k_mm_fin(
    const float* __restrict__ A, const float* __restrict__ W,
    const float* __restrict__ bias, float* __restrict__ out){
  int row = blockIdx.x*4 + (threadIdx.x >> 6);
  int lane = threadIdx.x & 63;
  float a0 = A[(size_t)row*128 + lane];
  float a1 = A[(size_t)row*128 + 64 + lane];
  float4 w0 = ((const float4*)W)[lane];
  float4 w1 = ((const float4*)W)[64 + lane];
  float p0 = fmaf(a1, w1.x, a0*w0.x);
  float p1 = fmaf(a1, w1.y, a0*w0.y);
  float p2 = fmaf(a1, w1.z, a0*w0.z);
  float p3 = fmaf(a1, w1.w, a0*w0.w);
  #pragma unroll
  for (int off = 32; off; off >>= 1){
    p0 += __shfl_xor(p0, off);
    p1 += __shfl_xor(p1, off);
    p2 += __shfl_xor(p2, off);
    p3 += __shfl_xor(p3, off);
  }
  if (lane == 0){
    float4 bv = *(const float4*)bias;
    *(float4*)&out[(size_t)row*4] = make_float4(p0+bv.x, p1+bv.y, p2+bv.z, p3+bv.w);
  }
}

// ---------------- launch ----------------
extern "C" void kernel_launch(void* const* d_in, const int* in_sizes, int n_in,
                              void* d_out, int out_size, void* d_ws, size_t ws_size,
                              hipStream_t stream){
  const float* x     = (const float*)d_in[0];
  const int*   ei    = (const int*)  d_in[1];
  const float* w_e1  = (const float*)d_in[2];
  const float* b_e1  = (const float*)d_in[3];
  const float* w_e2  = (const float*)d_in[4];
  const float* b_e2  = (const float*)d_in[5];
  const float* w_e3  = (const float*)d_in[6];
  const float* as_e3 = (const float*)d_in[7];
  const float* ad_e3 = (const float*)d_in[8];
  const float* b_e3  = (const float*)d_in[9];
  const float* w_d1  = (const float*)d_in[10];
  const float* b_d1  = (const float*)d_in[11];
  const float* w_d2  = (const float*)d_in[12];
  const float* b_d2  = (const float*)d_in[13];
  const float* w_d3  = (const float*)d_in[14];
  const float* as_d3 = (const float*)d_in[15];
  const float* ad_d3 = (const float*)d_in[16];
  const float* b_d3  = (const float*)d_in[17];
  const float* w_fc1 = (const float*)d_in[18];
  const float* b_fc1 = (const float*)d_in[19];
  const float* w_fc2 = (const float*)d_in[20];
  const float* b_fc2 = (const float*)d_in[21];
  const float* w_fin = (const float*)d_in[22];
  const float* b_fin = (const float*)d_in[23];

  char* ws = (char*)d_ws;
  size_t off = 0;
  auto alloc = [&](size_t bytes)->char*{
    char* p = ws + off;
    off += (bytes + 127) & ~size_t(127);
    return p;
  };
  int*   cnt       = (int*)  alloc((size_t)Nn*4);
  int*   fill      = (int*)  alloc((size_t)Nn*4);
  int*   row_start = (int*)  alloc((size_t)(Nn+1)*4);
  int*   csr       = (int*)  alloc((size_t)Ee*4);
  float* dinv      = (float*)alloc((size_t)Nn*4);
  float* aSb       = (float*)alloc((size_t)Nn*16);
  float* aDb       = (float*)alloc((size_t)Nn*16);
  float* X1        = (float*)alloc((size_t)Nn*64*4);
  float* X2        = (float*)alloc((size_t)Nn*128*4);
  float* bufA      = (float*)alloc((size_t)Nn*256*4);
  float* bufB      = (float*)alloc((size_t)Nn*512*4);
  float* bufC      = (float*)alloc((size_t)Nn*512*4);

  const int* srcp = ei;
  const int* dstp = ei + Ee;

  hipMemsetAsync(cnt, 0, (size_t)Nn*4, stream);
  hipMemsetAsync(fill, 0, (size_t)Nn*4, stream);
  k_count<<<(Ee+255)/256, 256, 0, stream>>>(dstp, cnt);
  k_scan<<<1, 1024, 0, stream>>>(cnt, row_start, dinv);
  k_scatter<<<(Ee+255)/256, 256, 0, stream>>>(srcp, dstp, row_start, fill, csr);

  // encoder1: x1 = relu(agg(x) @ W1 + b1)
  k_gcn_agg<32,false><<<Nn/4, 256, 0, stream>>>(x, dinv, row_start, csr, nullptr, nullptr, bufA);
  k_mm<32,64,1,true,true><<<dim3(Nn/32,1), 256, 0, stream>>>(bufA, w_e1, b_e1, X1);
  // encoder2: x2 = relu(agg(x1) @ W2 + b2)
  k_gcn_agg<64,false><<<Nn/4, 256, 0, stream>>>(X1, dinv, row_start, csr, nullptr, nullptr, bufA);
  k_mm<64,128,2,true,true><<<dim3(Nn/32,1), 256, 0, stream>>>(bufA, w_e2, b_e2, X2);
  // encoder3 (GAT): h3 = x2 @ W3; x3 = relu(gat_agg(h3) + b3)
  k_mm<128,512,4,false,false><<<dim3(Nn/32,2), 256, 0, stream>>>(X2, w_e3, nullptr, bufB);
  k_attn_coef<128><<<Nn/4, 256, 0, stream>>>(bufB, as_e3, ad_e3, aSb, aDb);
  k_gat_agg<512><<<Nn/4, 256, 0, stream>>>(bufB, aSb, aDb, row_start, csr, b_e3, bufC);
  // decoder1: h4 = relu(agg(x3 @ Wd1) + bd1) + x2
  k_mm<512,128,2,false,false><<<dim3(Nn/32,1), 256, 0, stream>>>(bufC, w_d1, nullptr, bufA);
  k_gcn_agg<128,true><<<Nn/4, 256, 0, stream>>>(bufA, dinv, row_start, csr, b_d1, X2, bufB);
  // decoder2: h5 = relu(agg(h4 @ Wd2) + bd2) + x1
  k_mm<128,64,1,false,false><<<dim3(Nn/32,1), 256, 0, stream>>>(bufB, w_d2, nullptr, bufC);
  k_gcn_agg<64,true><<<Nn/4, 256, 0, stream>>>(bufC, dinv, row_start, csr, b_d2, X1, bufA);
  // decoder3 (GAT): hd3 = h5 @ Wd3; h6 = relu(gat_agg(hd3) + bd3)
  k_mm<64,256,4,false,false><<<dim3(Nn/32,1), 256, 0, stream>>>(bufA, w_d3, nullptr, bufB);
  k_attn_coef<64><<<Nn/4, 256, 0, stream>>>(bufB, as_d3, ad_d3, aSb, aDb);
  k_gat_agg<256><<<Nn/4, 256, 0, stream>>>(bufB, aSb, aDb, row_start, csr, b_d3, bufC);
  // MLP head
  k_mm<256,256,4,true,true><<<dim3(Nn/32,1), 256, 0, stream>>>(bufC, w_fc1, b_fc1, bufA);
  k_mm<256,128,2,true,true><<<dim3(Nn/32,1), 256, 0, stream>>>(bufA, w_fc2, b_fc2, bufB);
  k_mm_fin<<<Nn/4, 256, 0, stream>>>(bufB, w_fin, b_fin, (float*)d_out);
}

// Round 2
// 588.835 us; speedup vs baseline: 1.0561x; 1.0561x over previous
//
#include <hip/hip_runtime.h>
#include <cstdint>
#include <cstddef>

static constexpr int Nn = 20000;
static constexpr int Ee = 320000;

__device__ __forceinline__ float lrelu02(float x){ return fmaxf(x, 0.2f*x); }

// ---------------- CSR build ----------------
__global__ void k_count(const int* __restrict__ dst, int* __restrict__ cnt){
  int e = blockIdx.x*256 + threadIdx.x;
  if (e < Ee) atomicAdd(&cnt[dst[e]], 1);
}

__global__ void k_scan(const int* __restrict__ cnt, int* __restrict__ row_start,
                       float* __restrict__ dinv){
  __shared__ int part[1024];
  int tid = threadIdx.x;
  const int PER = 20;                       // 1024*20 >= 20000
  int base = tid*PER;
  int s = 0;
  for (int i = 0; i < PER; ++i){ int idx = base+i; if (idx < Nn) s += cnt[idx]; }
  part[tid] = s; __syncthreads();
  for (int off = 1; off < 1024; off <<= 1){
    int v = (tid >= off) ? part[tid-off] : 0;
    __syncthreads();
    part[tid] += v;
    __syncthreads();
  }
  int run = (tid == 0) ? 0 : part[tid-1];
  for (int i = 0; i < PER; ++i){
    int idx = base+i;
    if (idx < Nn){
      row_start[idx] = run;
      int c = cnt[idx];
      run += c;
      dinv[idx] = rsqrtf((float)(c+1));     // +1 self-loop
    }
  }
  if (tid == 1023) row_start[Nn] = run;
}

__global__ void k_scatter(const int* __restrict__ src, const int* __restrict__ dst,
                          const int* __restrict__ row_start, int* __restrict__ fill,
                          int* __restrict__ csr){
  int e = blockIdx.x*256 + threadIdx.x;
  if (e < Ee){
    int d = dst[e];
    int pos = row_start[d] + atomicAdd(&fill[d], 1);
    csr[pos] = src[e];
  }
}

// ---------------- GCN aggregation: out[v] = dinv[v]*sum_u dinv[u]*h[u] + dinv[v]^2*h[v] ----------------
template<int C, bool POST>
__global__ __launch_bounds__(256) void k_gcn_agg(
    const float* __restrict__ h, const float* __restrict__ dinv,
    const int* __restrict__ row_start, const int* __restrict__ csr,
    const float* __restrict__ bias, const float* __restrict__ skip,
    float* __restrict__ out){
  int v = blockIdx.x*4 + (threadIdx.x >> 6);
  int lane = threadIdx.x & 63;
  int s = row_start[v], e = row_start[v+1];
  float dv = dinv[v];

  if constexpr (C == 32){
    int half = lane >> 5, c = lane & 31;
    float acc = 0.f;
    for (int i = s + half; i < e; i += 2){
      int u = csr[i];
      acc = fmaf(dinv[u], h[(size_t)u*32 + c], acc);
    }
    acc += __shfl_xor(acc, 32);
    float val = fmaf(acc, dv, h[(size_t)v*32 + c]*dv*dv);
    if (lane < 32) out[(size_t)v*32 + c] = val;
  } else if constexpr (C == 64){
    float acc = 0.f;
    for (int i = s; i < e; ++i){
      int u = csr[i];
      acc = fmaf(dinv[u], h[(size_t)u*64 + lane], acc);
    }
    float val = fmaf(acc, dv, h[(size_t)v*64 + lane]*dv*dv);
    if constexpr (POST){
      val = fmaxf(val + bias[lane], 0.f) + skip[(size_t)v*64 + lane];
    }
    out[(size_t)v*64 + lane] = val;
  } else {  // C == 128
    int c0 = lane*2;
    float ax = 0.f, ay = 0.f;
    for (int i = s; i < e; ++i){
      int u = csr[i];
      float du = dinv[u];
      float2 t = *(const float2*)&h[(size_t)u*128 + c0];
      ax = fmaf(du, t.x, ax);
      ay = fmaf(du, t.y, ay);
    }
    float2 hv = *(const float2*)&h[(size_t)v*128 + c0];
    float vx = fmaf(ax, dv, hv.x*dv*dv);
    float vy = fmaf(ay, dv, hv.y*dv*dv);
    if constexpr (POST){
      float2 bv = *(const float2*)&bias[c0];
      float2 sk = *(const float2*)&skip[(size_t)v*128 + c0];
      vx = fmaxf(vx + bv.x, 0.f) + sk.x;
      vy = fmaxf(vy + bv.y, 0.f) + sk.y;
    }
    *(float2*)&out[(size_t)v*128 + c0] = make_float2(vx, vy);
  }
}

// ---------------- fold attention vectors through W: wF[h][k] = sum_c W[k, h*C+c]*att[h][c] ----------------
template<int INC, int C>
__global__ void k_fold(const float* __restrict__ W, const float* __restrict__ as_,
                       const float* __restrict__ ad_, float* __restrict__ wsF,
                       float* __restrict__ wdF){
  int h = threadIdx.x >> 6, lane = threadIdx.x & 63;
  for (int k = lane; k < INC; k += 64){
    float s = 0.f, d = 0.f;
    #pragma unroll 4
    for (int c = 0; c < C; ++c){
      float wv = W[(size_t)k*(4*C) + h*C + c];
      s = fmaf(wv, as_[h*C + c], s);
      d = fmaf(wv, ad_[h*C + c], d);
    }
    wsF[h*INC + k] = s;
    wdF[h*INC + k] = d;
  }
}

// ---------------- attention coefficients from the INPUT: aS[n,h] = <X[n,:], wsF[h,:]> ----------------
template<int INC>
__global__ __launch_bounds__(256) void k_attn_in(
    const float* __restrict__ X, const float* __restrict__ wsF, const float* __restrict__ wdF,
    float* __restrict__ aS, float* __restrict__ aD){
  int v = blockIdx.x*4 + (threadIdx.x >> 6);
  int lane = threadIdx.x & 63;
  float x0 = X[(size_t)v*INC + lane];
  float x1 = (INC == 128) ? X[(size_t)v*INC + 64 + lane] : 0.f;
  float s[4], d[4];
  #pragma unroll
  for (int h = 0; h < 4; ++h){
    s[h] = x0*wsF[h*INC + lane];
    d[h] = x0*wdF[h*INC + lane];
    if constexpr (INC == 128){
      s[h] = fmaf(x1, wsF[h*INC + 64 + lane], s[h]);
      d[h] = fmaf(x1, wdF[h*INC + 64 + lane], d[h]);
    }
  }
  #pragma unroll
  for (int off = 32; off; off >>= 1){
    #pragma unroll
    for (int h = 0; h < 4; ++h){
      s[h] += __shfl_xor(s[h], off);
      d[h] += __shfl_xor(d[h], off);
    }
  }
  if (lane == 0){
    *(float4*)&aS[v*4] = make_float4(s[0], s[1], s[2], s[3]);
    *(float4*)&aD[v*4] = make_float4(d[0], d[1], d[2], d[3]);
  }
}

// ---------------- GAT aggregation on the INPUT side: agg[v,h,:] = sum_u alpha^h_vu X[u,:] ----------------
template<int INC>   // 128 (e3) or 64 (d3)
__global__ __launch_bounds__(256) void k_gat_agg_in(
    const float* __restrict__ X, const float* __restrict__ aS, const float* __restrict__ aD,
    const int* __restrict__ row_start, const int* __restrict__ csr,
    float* __restrict__ agg){
  int v = blockIdx.x*4 + (threadIdx.x >> 6);
  int lane = threadIdx.x & 63;
  int s0 = row_start[v], e0 = row_start[v+1];

  float4 tD = *(const float4*)&aD[v*4];
  float ad[4] = {tD.x, tD.y, tD.z, tD.w};
  float4 tS = *(const float4*)&aS[v*4];
  float lself[4];
  #pragma unroll
  for (int h = 0; h < 4; ++h) lself[h] = lrelu02(((const float*)&tS)[h] + ad[h]);

  // pass 1: online (max, sumexp) per head; lane 0 seeds the self-loop
  float m[4], sd[4];
  #pragma unroll
  for (int h = 0; h < 4; ++h){
    m[h]  = (lane == 0) ? lself[h] : -1e30f;
    sd[h] = (lane == 0) ? 1.f : 0.f;
  }
  for (int i = s0 + lane; i < e0; i += 64){
    int u = csr[i];
    float4 a4 = *(const float4*)&aS[u*4];
    float av[4] = {a4.x, a4.y, a4.z, a4.w};
    #pragma unroll
    for (int h = 0; h < 4; ++h){
      float l  = lrelu02(av[h] + ad[h]);
      float mn = fmaxf(m[h], l);
      sd[h] = sd[h]*__expf(m[h]-mn) + __expf(l-mn);
      m[h] = mn;
    }
  }
  #pragma unroll
  for (int off = 32; off; off >>= 1){
    #pragma unroll
    for (int h = 0; h < 4; ++h){
      float mo = __shfl_xor(m[h], off);
      float so = __shfl_xor(sd[h], off);
      float mn = fmaxf(m[h], mo);
      sd[h] = sd[h]*__expf(m[h]-mn) + so*__expf(mo-mn);
      m[h] = mn;
    }
  }
  float rd[4], als[4];
  #pragma unroll
  for (int h = 0; h < 4; ++h){
    rd[h]  = 1.f / sd[h];
    als[h] = __expf(lself[h] - m[h]) * rd[h];
  }

  // pass 2: weighted input aggregation
  if constexpr (INC == 128){
    int c0 = lane*2;
    float2 xv = *(const float2*)&X[(size_t)v*128 + c0];
    float2 acc[4];
    #pragma unroll
    for (int h = 0; h < 4; ++h) acc[h] = make_float2(als[h]*xv.x, als[h]*xv.y);
    for (int i = s0; i < e0; ++i){
      int u = csr[i];
      float4 a4 = *(const float4*)&aS[u*4];
      float av[4] = {a4.x, a4.y, a4.z, a4.w};
      float2 xu = *(const float2*)&X[(size_t)u*128 + c0];
      #pragma unroll
      for (int h = 0; h < 4; ++h){
        float al = __expf(lrelu02(av[h] + ad[h]) - m[h]) * rd[h];
        acc[h].x = fmaf(al, xu.x, acc[h].x);
        acc[h].y = fmaf(al, xu.y, acc[h].y);
      }
    }
    #pragma unroll
    for (int h = 0; h < 4; ++h)
      *(float2*)&agg[(size_t)v*512 + h*128 + c0] = acc[h];
  } else {  // INC == 64
    float xv = X[(size_t)v*64 + lane];
    float acc[4];
    #pragma unroll
    for (int h = 0; h < 4; ++h) acc[h] = als[h]*xv;
    for (int i = s0; i < e0; ++i){
      int u = csr[i];
      float4 a4 = *(const float4*)&aS[u*4];
      float av[4] = {a4.x, a4.y, a4.z, a4.w};
      float xu = X[(size_t)u*64 + lane];
      #pragma unroll
      for (int h = 0; h < 4; ++h){
        float al = __expf(lrelu02(av[h] + ad[h]) - m[h]) * rd[h];
        acc[h] = fmaf(al, xu, acc[h]);
      }
    }
    #pragma unroll
    for (int h = 0; h < 4; ++h)
      agg[(size_t)v*256 + h*64 + lane] = acc[h];
  }
}

// ---------------- per-head block matmul: out[n, h*OUTC+j] = sum_k agg[n,h,k] * W[k, h*OUTC+j] ----------------
// out = relu(. + bias). grid = (Nn/32, 4 heads)
template<int INC, int OUTC, int CP>
__global__ __launch_bounds__(256) void k_mm_head(
    const float* __restrict__ A, const float* __restrict__ W,
    const float* __restrict__ bias, float* __restrict__ out){
  __shared__ float As[32*INC];
  const int tid = threadIdx.x;
  const int rb  = blockIdx.x;
  const int h   = blockIdx.y;
  const int J   = 4*OUTC;

  #pragma unroll 2
  for (int i = tid; i < 32*INC/4; i += 256){
    int row = i / (INC/4), c4 = i % (INC/4);
    ((float4*)As)[i] = *(const float4*)&A[(size_t)(rb*32+row)*(4*INC) + h*INC + c4*4];
  }
  __syncthreads();

  const int wave = tid >> 6, lane = tid & 63;
  const int r0 = wave*8;
  const int col0 = h*OUTC + lane;

  float acc[8][CP];
  #pragma unroll
  for (int r = 0; r < 8; ++r)
    #pragma unroll
    for (int c = 0; c < CP; ++c) acc[r][c] = 0.f;

  for (int k0 = 0; k0 < INC; k0 += 4){
    float4 a4[8];
    #pragma unroll
    for (int r = 0; r < 8; ++r) a4[r] = *(const float4*)&As[(r0+r)*INC + k0];
    #pragma unroll
    for (int kk = 0; kk < 4; ++kk){
      float wv[CP];
      #pragma unroll
      for (int c = 0; c < CP; ++c) wv[c] = W[(size_t)(k0+kk)*J + col0 + c*64];
      #pragma unroll
      for (int r = 0; r < 8; ++r){
        float a = (kk==0) ? a4[r].x : (kk==1) ? a4[r].y : (kk==2) ? a4[r].z : a4[r].w;
        #pragma unroll
        for (int c = 0; c < CP; ++c) acc[r][c] = fmaf(a, wv[c], acc[r][c]);
      }
    }
  }

  #pragma unroll
  for (int c = 0; c < CP; ++c){
    int col = col0 + c*64;
    float bv = bias[col];
    #pragma unroll
    for (int r = 0; r < 8; ++r){
      float val = fmaxf(acc[r][c] + bv, 0.f);
      out[(size_t)(rb*32 + r0 + r)*J + col] = val;
    }
  }
}

// ---------------- dense matmul: out[n,j] = sum_k A[n,k]*W[k,j] (+bias)(+relu) ----------------
template<int K, int J, int CP, bool BIAS, bool RELU>
__global__ __launch_bounds__(256) void k_mm(
    const float* __restrict__ A, const float* __restrict__ W,
    const float* __restrict__ bias, float* __restrict__ out){
  __shared__ float As[32*K];
  const int tid = threadIdx.x;
  const int rb  = blockIdx.x;

  const float4* srcp = (const float4*)(A + (size_t)rb*32*K);
  float4* dstS = (float4*)As;
  #pragma unroll 4
  for (int i = tid; i < 32*K/4; i += 256) dstS[i] = srcp[i];
  __syncthreads();

  const int wave = tid >> 6, lane = tid & 63;
  const int r0 = wave*8;
  const int col0 = blockIdx.y*(64*CP) + lane;

  float acc[8][CP];
  #pragma unroll
  for (int r = 0; r < 8; ++r)
    #pragma unroll
    for (int c = 0; c < CP; ++c) acc[r][c] = 0.f;

  for (int k0 = 0; k0 < K; k0 += 4){
    float4 a4[8];
    #pragma unroll
    for (int r = 0; r < 8; ++r) a4[r] = *(const float4*)&As[(r0+r)*K + k0];
    #pragma unroll
    for (int kk = 0; kk < 4; ++kk){
      float wv[CP];
      #pragma unroll
      for (int c = 0; c < CP; ++c) wv[c] = W[(size_t)(k0+kk)*J + col0 + c*64];
      #pragma unroll
      for (int r = 0; r < 8; ++r){
        float a = (kk==0) ? a4[r].x : (kk==1) ? a4[r].y : (kk==2) ? a4[r].z : a4[r].w;
        #pragma unroll
        for (int c = 0; c < CP; ++c) acc[r][c] = fmaf(a, wv[c], acc[r][c]);
      }
    }
  }

  #pragma unroll
  for (int c = 0; c < CP; ++c){
    int col = col0 + c*64;
    float bv = 0.f;
    if constexpr (BIAS) bv = bias[col];
    #pragma unroll
    for (int r = 0; r < 8; ++r){
      float val = acc[r][c] + bv;
      if constexpr (RELU) val = fmaxf(val, 0.f);
      out[(size_t)(rb*32 + r0 + r)*J + col] = val;
    }
  }
}

// ---------------- final 128 -> 4 matmul (+bias), one wave per row ----------------
__global__ __launch_bounds__(256) void k_mm_fin(
    const float* __restrict__ A, const float* __restrict__ W,
    const float* __restrict__ bias, float* __restrict__ out){
  int row = blockIdx.x*4 + (threadIdx.x >> 6);
  int lane = threadIdx.x & 63;
  float a0 = A[(size_t)row*128 + lane];
  float a1 = A[(size_t)row*128 + 64 + lane];
  float4 w0 = ((const float4*)W)[lane];
  float4 w1 = ((const float4*)W)[64 + lane];
  float p0 = fmaf(a1, w1.x, a0*w0.x);
  float p1 = fmaf(a1, w1.y, a0*w0.y);
  float p2 = fmaf(a1, w1.z, a0*w0.z);
  float p3 = fmaf(a1, w1.w, a0*w0.w);
  #pragma unroll
  for (int off = 32; off; off >>= 1){
    p0 += __shfl_xor(p0, off);
    p1 += __shfl_xor(p1, off);
    p2 += __shfl_xor(p2, off);
    p3 += __shfl_xor(p3, off);
  }
  if (lane == 0){
    float4 bv = *(const float4*)bias;
    *(float4*)&out[(size_t)row*4] = make_float4(p0+bv.x, p1+bv.y, p2+bv.z, p3+bv.w);
  }
}

// ---------------- launch ----------------
extern "C" void kernel_launch(void* const* d_in, const int* in_sizes, int n_in,
                              void* d_out, int out_size, void* d_ws, size_t ws_size,
                              hipStream_t stream){
  const float* x     = (const float*)d_in[0];
  const int*   ei    = (const int*)  d_in[1];
  const float* w_e1  = (const float*)d_in[2];
  const float* b_e1  = (const float*)d_in[3];
  const float* w_e2  = (const float*)d_in[4];
  const float* b_e2  = (const float*)d_in[5];
  const float* w_e3  = (const float*)d_in[6];
  const float* as_e3 = (const float*)d_in[7];
  const float* ad_e3 = (const float*)d_in[8];
  const float* b_e3  = (const float*)d_in[9];
  const float* w_d1  = (const float*)d_in[10];
  const float* b_d1  = (const float*)d_in[11];
  const float* w_d2  = (const float*)d_in[12];
  const float* b_d2  = (const float*)d_in[13];
  const float* w_d3  = (const float*)d_in[14];
  const float* as_d3 = (const float*)d_in[15];
  const float* ad_d3 = (const float*)d_in[16];
  const float* b_d3  = (const float*)d_in[17];
  const float* w_fc1 = (const float*)d_in[18];
  const float* b_fc1 = (const float*)d_in[19];
  const float* w_fc2 = (const float*)d_in[20];
  const float* b_fc2 = (const float*)d_in[21];
  const float* w_fin = (const float*)d_in[22];
  const float* b_fin = (const float*)d_in[23];

  char* ws = (char*)d_ws;
  size_t off = 0;
  auto alloc = [&](size_t bytes)->char*{
    char* p = ws + off;
    off += (bytes + 127) & ~size_t(127);
    return p;
  };
  int*   cnt       = (int*)  alloc((size_t)Nn*4);
  int*   fill      = (int*)  alloc((size_t)Nn*4);
  int*   row_start = (int*)  alloc((size_t)(Nn+1)*4);
  int*   csr       = (int*)  alloc((size_t)Ee*4);
  float* dinv      = (float*)alloc((size_t)Nn*4);
  float* aSb       = (float*)alloc((size_t)Nn*16);
  float* aDb       = (float*)alloc((size_t)Nn*16);
  float* wsF_e3    = (float*)alloc(4*128*4);
  float* wdF_e3    = (float*)alloc(4*128*4);
  float* wsF_d3    = (float*)alloc(4*64*4);
  float* wdF_d3    = (float*)alloc(4*64*4);
  float* X1        = (float*)alloc((size_t)Nn*64*4);
  float* X2        = (float*)alloc((size_t)Nn*128*4);
  float* bufA      = (float*)alloc((size_t)Nn*256*4);
  float* bufB      = (float*)alloc((size_t)Nn*512*4);
  float* bufC      = (float*)alloc((size_t)Nn*512*4);

  const int* srcp = ei;
  const int* dstp = ei + Ee;

  hipMemsetAsync(cnt, 0, (size_t)Nn*4, stream);
  hipMemsetAsync(fill, 0, (size_t)Nn*4, stream);
  k_count<<<(Ee+255)/256, 256, 0, stream>>>(dstp, cnt);
  k_scan<<<1, 1024, 0, stream>>>(cnt, row_start, dinv);
  k_scatter<<<(Ee+255)/256, 256, 0, stream>>>(srcp, dstp, row_start, fill, csr);
  // attention folds depend only on weights — launch early
  k_fold<128,128><<<1, 256, 0, stream>>>(w_e3, as_e3, ad_e3, wsF_e3, wdF_e3);
  k_fold<64,64><<<1, 256, 0, stream>>>(w_d3, as_d3, ad_d3, wsF_d3, wdF_d3);

  // encoder1: x1 = relu(agg(x) @ W1 + b1)
  k_gcn_agg<32,false><<<Nn/4, 256, 0, stream>>>(x, dinv, row_start, csr, nullptr, nullptr, bufA);
  k_mm<32,64,1,true,true><<<dim3(Nn/32,1), 256, 0, stream>>>(bufA, w_e1, b_e1, X1);
  // encoder2: x2 = relu(agg(x1) @ W2 + b2)
  k_gcn_agg<64,false><<<Nn/4, 256, 0, stream>>>(X1, dinv, row_start, csr, nullptr, nullptr, bufA);
  k_mm<64,128,2,true,true><<<dim3(Nn/32,1), 256, 0, stream>>>(bufA, w_e2, b_e2, X2);
  // encoder3 (GAT, input-side aggregation): x3 = relu(blockmm(gat_agg(x2)) + b3)
  k_attn_in<128><<<Nn/4, 256, 0, stream>>>(X2, wsF_e3, wdF_e3, aSb, aDb);
  k_gat_agg_in<128><<<Nn/4, 256, 0, stream>>>(X2, aSb, aDb, row_start, csr, bufB);
  k_mm_head<128,128,2><<<dim3(Nn/32,4), 256, 0, stream>>>(bufB, w_e3, b_e3, bufC);
  // decoder1: h4 = relu(agg(x3 @ Wd1) + bd1) + x2
  k_mm<512,128,2,false,false><<<dim3(Nn/32,1), 256, 0, stream>>>(bufC, w_d1, nullptr, bufA);
  k_gcn_agg<128,true><<<Nn/4, 256, 0, stream>>>(bufA, dinv, row_start, csr, b_d1, X2, bufB);
  // decoder2: h5 = relu(agg(h4 @ Wd2) + bd2) + x1
  k_mm<128,64,1,false,false><<<dim3(Nn/32,1), 256, 0, stream>>>(bufB, w_d2, nullptr, bufC);
  k_gcn_agg<64,true><<<Nn/4, 256, 0, stream>>>(bufC, dinv, row_start, csr, b_d2, X1, bufA);
  // decoder3 (GAT, input-side aggregation): h6 = relu(blockmm(gat_agg(h5)) + bd3)
  k_attn_in<64><<<Nn/4, 256, 0, stream>>>(bufA, wsF_d3, wdF_d3, aSb, aDb);
  k_gat_agg_in<64><<<Nn/4, 256, 0, stream>>>(bufA, aSb, aDb, row_start, csr, bufB);
  k_mm_head<64,64,1><<<dim3(Nn/32,4), 256, 0, stream>>>(bufB, w_d3, b_d3, bufC);
  // MLP head
  k_mm<256,256,4,true,true><<<dim3(Nn/32,1), 256, 0, stream>>>(bufC, w_fc1, b_fc1, bufA);
  k_mm<256,128,2,true,true><<<dim3(Nn/32,1), 256, 0, stream>>>(bufA, w_fc2, b_fc2, bufB);
  k_mm_fin<<<Nn/4, 256, 0, stream>>>(bufB, w_fin, b_fin, (float*)d_out);
}